// Round 8
// baseline (186.249 us; speedup 1.0000x reference)
//
#include <hip/hip_runtime.h>
#include <stdint.h>

typedef __bf16 bf16_t;
typedef bf16_t bf16x8 __attribute__((ext_vector_type(8)));
typedef float f32x4 __attribute__((ext_vector_type(4)));
typedef float f32x16 __attribute__((ext_vector_type(16)));
typedef unsigned short us8 __attribute__((ext_vector_type(8)));
typedef unsigned short us4 __attribute__((ext_vector_type(4)));
typedef unsigned int u32x4 __attribute__((ext_vector_type(4)));

#define B_ 4
#define T_ 4096
#define C_ 1024
#define D_ 128

#define NCHUNK_PB 72    // per batch: sum over 16 q-tiles(256) of ceil((4jt+4)/8)
#define QSCALE 0.12751744f  // (1/sqrt(128)) * log2(e), folded into Q
#define M0 14.0f            // fixed softmax base (log2 domain); cancels in combine

__device__ __forceinline__ uint16_t f2bf(float f) {
    union { float f; uint32_t u; } v; v.f = f;
    uint32_t u = v.u;
    uint32_t r = (u + 0x7fffu + ((u >> 16) & 1u)) >> 16;
    return (uint16_t)r;
}

// round-half-up bf16 (2 VALU)
__device__ __forceinline__ uint16_t bfru(float f) {
    return (uint16_t)((__float_as_uint(f) + 0x8000u) >> 16);
}

__device__ __forceinline__ float bf2f(uint16_t u) {
    return __uint_as_float((uint32_t)u << 16);
}

// pack 2 f32 -> u32 of 2 bf16 (lo=a, hi=b); no builtin on gfx950 (T12 recipe)
__device__ __forceinline__ uint32_t cvtpk(float a, float b) {
    uint32_t r;
    asm("v_cvt_pk_bf16_f32 %0, %1, %2" : "=v"(r) : "v"(a), "v"(b));
    return r;
}

// v_permlane32_swap_b32: exchanges a.lanes[32:63] <-> b.lanes[0:31].
__device__ __forceinline__ void pl32swap(uint32_t& a, uint32_t& b) {
    asm("v_permlane32_swap_b32 %0, %1" : "+v"(a), "+v"(b));
}

// async global->LDS DMA, 16 B per lane. LDS dest = wave-uniform base + lane*16.
__device__ __forceinline__ void gload_lds16(const void* g, void* l) {
    __builtin_amdgcn_global_load_lds(
        (const __attribute__((address_space(1))) void*)g,
        (__attribute__((address_space(3))) void*)l, 16, 0, 0);
}

// ---------------------------------------------------------------------------
// Kernel 1: W[C,D] fp32 -> WT[w][n][k] bf16 (transposed), w in {q,k,v}
// ---------------------------------------------------------------------------
__global__ __launch_bounds__(256) void prep_w(const float* __restrict__ Wq,
                                              const float* __restrict__ Wk,
                                              const float* __restrict__ Wv,
                                              uint16_t* __restrict__ WT) {
    int idx = blockIdx.x * 256 + threadIdx.x;
    if (idx >= 3 * D_ * C_) return;
    int w   = idx / (D_ * C_);
    int rem = idx - w * (D_ * C_);
    int n   = rem / C_;
    int k   = rem - n * C_;
    const float* W = (w == 0) ? Wq : (w == 1) ? Wk : Wv;
    WT[idx] = f2bf(W[(size_t)k * D_ + n]);
}

// ---------------------------------------------------------------------------
// Kernel 2 (R11): wsel-SPLIT QKV projection — unchanged (verified, <47us).
// ---------------------------------------------------------------------------
__global__ __launch_bounds__(256, 3) void qkv_split(const float* __restrict__ x,
                                                    const uint16_t* __restrict__ WT,
                                                    uint16_t* __restrict__ qb,
                                                    uint16_t* __restrict__ kb,
                                                    uint16_t* __restrict__ vT) {
    __shared__ __align__(16) float    A_lds[2][64 * 32];    // 2 x 8 KB (fp32)
    __shared__ __align__(16) uint16_t W_lds[2][128 * 32];   // 2 x 8 KB (bf16)

    int tid  = threadIdx.x;
    int lane = tid & 63;
    int wave = tid >> 6;          // 0..3
    int quad = lane >> 4;
    int lx   = lane & 15;
    int wm   = wave >> 1;         // 0..1 : 32-row half
    int wn   = wave & 1;          // 0..1 : 64-col half

    int bx   = blockIdx.x;
    int wsel = bx >> 8;           // 0..2 (Q/K/V)
    int m0   = (bx & 255) * 64;
    const uint16_t* Wp = WT + (size_t)wsel * (D_ * C_);

    auto issue_ab = [&](int bi, int k0) {
#pragma unroll
        for (int j = 0; j < 2; j++) {
            int rbase = wave * 16 + j * 8;
            int row   = rbase + (lane >> 3);
            int gch   = (lane & 7) ^ (row & 7);
            gload_lds16(x + (size_t)(m0 + row) * C_ + k0 + gch * 4,
                        &A_lds[bi][rbase * 32]);
        }
#pragma unroll
        for (int j = 0; j < 2; j++) {
            int rbase = wave * 32 + j * 16;
            int row   = rbase + (lane >> 2);
            int gch   = (lane & 3) ^ ((row >> 1) & 3);
            gload_lds16(Wp + (size_t)row * C_ + k0 + gch * 8,
                        &W_lds[bi][rbase * 32]);
        }
    };

    f32x4 acc[2][4];
#pragma unroll
    for (int mf = 0; mf < 2; mf++)
#pragma unroll
        for (int nf = 0; nf < 4; nf++)
            acc[mf][nf] = (f32x4){0.f, 0.f, 0.f, 0.f};

    issue_ab(0, 0);   // prologue prefetch
    int cur = 0;

    for (int k0 = 0; k0 < C_; k0 += 32) {
        __syncthreads();
        if (k0 + 32 < C_) issue_ab(cur ^ 1, k0 + 32);

        bf16x8 af[2];
#pragma unroll
        for (int mf = 0; mf < 2; mf++) {
            int arow = wm * 32 + mf * 16 + lx;
            const float* ar = &A_lds[cur][arow * 32];
            f32x4 a0 = *(const f32x4*)&ar[((2 * quad) ^ (arow & 7)) * 4];
            f32x4 a1 = *(const f32x4*)&ar[((2 * quad + 1) ^ (arow & 7)) * 4];
            u32x4 w = (u32x4){cvtpk(a0[0], a0[1]), cvtpk(a0[2], a0[3]),
                              cvtpk(a1[0], a1[1]), cvtpk(a1[2], a1[3])};
            af[mf] = *(bf16x8*)&w;
        }

#pragma unroll
        for (int nf = 0; nf < 4; nf++) {
            int n = wn * 64 + nf * 16 + lx;
            bf16x8 wf = *(const bf16x8*)&W_lds[cur][n * 32 + ((quad ^ ((n >> 1) & 3)) * 8)];
            acc[0][nf] = __builtin_amdgcn_mfma_f32_16x16x32_bf16(af[0], wf, acc[0][nf], 0, 0, 0);
            acc[1][nf] = __builtin_amdgcn_mfma_f32_16x16x32_bf16(af[1], wf, acc[1][nf], 0, 0, 0);
        }
        cur ^= 1;
    }

#pragma unroll
    for (int mf = 0; mf < 2; mf++) {
        int mrow0 = m0 + wm * 32 + mf * 16 + quad * 4;
        int batch = mrow0 >> 12;
        int t     = mrow0 & 4095;
#pragma unroll
        for (int nf = 0; nf < 4; nf++) {
            int n = wn * 64 + nf * 16 + lx;
            if (wsel == 0) {
#pragma unroll
                for (int r = 0; r < 4; r++)
                    qb[(size_t)(mrow0 + r) * D_ + n] = bfru(acc[mf][nf][r] * QSCALE);
            } else if (wsel == 1) {
#pragma unroll
                for (int r = 0; r < 4; r++)
                    kb[(size_t)(mrow0 + r) * D_ + n] = bfru(acc[mf][nf][r]);
            } else {
                us4 pv;
#pragma unroll
                for (int r = 0; r < 4; r++) pv[r] = bfru(acc[mf][nf][r]);
                *(us4*)&vT[(size_t)batch * D_ * T_ + (size_t)n * T_ + t] = pv;
            }
        }
    }
}

// ---------------------------------------------------------------------------
// Kernel 3 (R12): split-K flash attention, T12 in-reg P, 8-WAVE blocks.
// Q-tile 128 -> 256 rows, 512 threads: per-wave state UNCHANGED (~100 VGPR,
// the R10 lesson), but waves/CU doubles (2 blocks x 8 waves = 16/CU = 4/SIMD,
// under the 128-VGPR cap) and block-tile-iters halve (4224 -> 2176) -> half
// the staged K/V traffic and DMA ops. Grid 288 <= resident capacity, so all
// blocks co-resident; longest-first bounds the tail. LDS still 64 KB.
// ---------------------------------------------------------------------------
__global__ __launch_bounds__(512, 2) void attn(const uint16_t* __restrict__ qb,
                                               const uint16_t* __restrict__ kb,
                                               const uint16_t* __restrict__ vT,
                                               uint16_t* __restrict__ part,
                                               float* __restrict__ ml) {
    __shared__ __align__(16) uint16_t K_lds[2][64 * 128];    // 2 x 16384 B
    __shared__ __align__(16) uint16_t V_lds[2][128 * 64];    // 2 x 16384 B

    int tid  = threadIdx.x;
    int lane = tid & 63;
    int wave = tid >> 6;    // 0..7
    int q31  = lane & 31;   // q column (and key-row / d-row index in frags)
    int hi   = lane >> 5;   // kb group

    // decode blockIdx -> (batch, logical chunk L), longest chunks first.
    // q-tile jt in [0,16): 4jt+4 key-tiles(64), nc(jt) = (jt>>1)+1 chunks.
    // cumulative chunks before group a (jt = 2a): a(a+1).
    int batch = blockIdx.x & 3;
    int L     = NCHUNK_PB - 1 - (blockIdx.x >> 2);
    int a = 0;
    while (a < 7 && (a + 1) * (a + 2) <= L) a++;
    int rem   = L - a * (a + 1);
    int jt    = 2 * a + rem / (a + 1);
    int chunk = rem - (rem / (a + 1)) * (a + 1);
    int lidx  = batch * NCHUNK_PB + L;

    int q0     = jt * 256;
    int st0    = chunk * 8;
    int ntiles = min(8, 4 * jt + 4 - st0);

    // issue one K+V 64-key tile into buffer bi via DMA (8 waves: 2+2 ops/wave).
    auto issue_kv = [&](int bi, int tile) {
        int s0i = tile * 64;
        const uint16_t* kB = kb + (size_t)(batch * T_ + s0i) * D_;
#pragma unroll
        for (int j = 0; j < 2; j++) {
            int row = wave * 8 + j * 4 + (lane >> 4);
            int gch = (lane & 15) ^ (row & 7);
            gload_lds16(kB + (size_t)row * D_ + gch * 8,
                        &K_lds[bi][(wave * 8 + j * 4) * 128]);
        }
        const uint16_t* vB = vT + (size_t)batch * D_ * T_ + s0i;
#pragma unroll
        for (int j = 0; j < 2; j++) {
            int row = wave * 16 + j * 8 + (lane >> 3);
            int gch = (lane & 7) ^ (row & 7);
            gload_lds16(vB + (size_t)row * T_ + gch * 8,
                        &V_lds[bi][(wave * 16 + j * 8) * 64]);
        }
    };

    // Q fragments (B operand): lane = q + 32*kb holds d = kc*16 + kb*8 + j
    bf16x8 qf[8];
    {
        const uint16_t* qp = qb + (size_t)(batch * T_ + q0 + wave * 32 + q31) * D_ + hi * 8;
#pragma unroll
        for (int kc = 0; kc < 8; kc++) qf[kc] = *(const bf16x8*)(qp + kc * 16);
    }

    f32x16 o[4];
#pragma unroll
    for (int i = 0; i < 4; i++)
#pragma unroll
        for (int r = 0; r < 16; r++) o[i][r] = 0.f;
    float lsum = 0.f;

    issue_kv(0, st0);   // prologue prefetch
    int cur = 0;

    for (int it = 0; it < ntiles; it++) {
        int s0 = (st0 + it) * 64;
        // drains this wave's DMA (vmcnt(0) implicit) -> buf[cur] ready;
        // also guarantees all waves finished reading buf[cur^1] last iter.
        __syncthreads();
        if (it + 1 < ntiles) issue_kv(cur ^ 1, st0 + it + 1);

        // S^T = K Q^T (A = K-frag, B = Q-frag), 2 s-tiles of 32
        f32x16 st[2];
#pragma unroll
        for (int nt = 0; nt < 2; nt++)
#pragma unroll
            for (int r = 0; r < 16; r++) st[nt][r] = 0.f;
        __builtin_amdgcn_s_setprio(1);
#pragma unroll
        for (int kc = 0; kc < 8; kc++)
#pragma unroll
            for (int nt = 0; nt < 2; nt++) {
                int row = nt * 32 + q31;
                bf16x8 kf = *(const bf16x8*)&K_lds[cur][row * 128 + (((kc * 2 + hi) ^ (row & 7)) * 8)];
                st[nt] = __builtin_amdgcn_mfma_f32_32x32x16_bf16(kf, qf[kc], st[nt], 0, 0, 0);
            }
        __builtin_amdgcn_s_setprio(0);

        // causal mask on diagonal-region tiles (wave-uniform branch)
        if (st0 + it >= 4 * jt) {
            int qg = q0 + wave * 32 + q31;
#pragma unroll
            for (int nt = 0; nt < 2; nt++)
#pragma unroll
                for (int r = 0; r < 16; r++) {
                    int sg = s0 + nt * 32 + (r & 3) + 8 * (r >> 2) + 4 * hi;
                    if (sg > qg) st[nt][r] = -INFINITY;
                }
        }

        // p = exp2(s - M0); accumulate denominator per-lane (one q per lane)
#pragma unroll
        for (int nt = 0; nt < 2; nt++)
#pragma unroll
            for (int r = 0; r < 16; r++) {
                st[nt][r] = exp2f(st[nt][r] - M0);
                lsum += st[nt][r];
            }

        // build PV A-frags in-register: 16 cvt_pk + 8 permlane32_swap.
        // pa[sb] reg j at lane(q,hi) = P[q][sb*16 + hi*8 + 2j, +2j+1]
        bf16x8 pa[4];
#pragma unroll
        for (int nt = 0; nt < 2; nt++) {
            uint32_t x0 = cvtpk(st[nt][0],  st[nt][1]);
            uint32_t x1 = cvtpk(st[nt][2],  st[nt][3]);
            uint32_t y0 = cvtpk(st[nt][4],  st[nt][5]);
            uint32_t y1 = cvtpk(st[nt][6],  st[nt][7]);
            pl32swap(x0, y0);
            pl32swap(x1, y1);
            u32x4 w0 = (u32x4){x0, x1, y0, y1};
            pa[2 * nt] = *(bf16x8*)&w0;
            uint32_t z0 = cvtpk(st[nt][8],  st[nt][9]);
            uint32_t z1 = cvtpk(st[nt][10], st[nt][11]);
            uint32_t t0 = cvtpk(st[nt][12], st[nt][13]);
            uint32_t t1 = cvtpk(st[nt][14], st[nt][15]);
            pl32swap(z0, t0);
            pl32swap(z1, t1);
            u32x4 w1 = (u32x4){z0, z1, t0, t1};
            pa[2 * nt + 1] = *(bf16x8*)&w1;
        }

        // O += P V : A = pa[sb] (q x 16s), B = V-frag from vT layout [d][s]
        __builtin_amdgcn_s_setprio(1);
#pragma unroll
        for (int sb = 0; sb < 4; sb++)
#pragma unroll
            for (int ntd = 0; ntd < 4; ntd++) {
                int row = ntd * 32 + q31;
                bf16x8 vf = *(const bf16x8*)&V_lds[cur][row * 64 + (((sb * 2 + hi) ^ (row & 7)) * 8)];
                o[ntd] = __builtin_amdgcn_mfma_f32_32x32x16_bf16(pa[sb], vf, o[ntd], 0, 0, 0);
            }
        __builtin_amdgcn_s_setprio(0);
        cur ^= 1;
    }

    // each q's denominator is split across lane and lane^32
    lsum += __shfl_xor(lsum, 32, 64);

    // write unnormalized partial (bf16) + l at the LOGICAL index.
    // O tile: col=lane&31 = d (within ntd*32), row = (r&3)+8*(r>>2)+4*hi = q
    uint16_t* pp = part + (size_t)lidx * (256 * 128);
#pragma unroll
    for (int ntd = 0; ntd < 4; ntd++)
#pragma unroll
        for (int r = 0; r < 16; r++) {
            int lrow = wave * 32 + (r & 3) + 8 * (r >> 2) + 4 * hi;
            pp[lrow * 128 + ntd * 32 + q31] = bfru(o[ntd][r]);
        }
    if (lane < 32)
        ml[(size_t)lidx * 256 + wave * 32 + q31] = lsum;
}

// ---------------------------------------------------------------------------
// Kernel 4: combine split-K partials: plain sums (fixed M0 cancels).
// Grid = (batch, jt256, row-quarter): 256 blocks; block = 64 rows x 128 cols.
// ---------------------------------------------------------------------------
__global__ __launch_bounds__(256) void combine(const uint16_t* __restrict__ part,
                                               const float* __restrict__ ml,
                                               float* __restrict__ out) {
    int bidx  = blockIdx.x;
    int rq    = bidx & 3;
    int jt    = (bidx >> 2) & 15;
    int batch = bidx >> 6;
    int a     = jt >> 1;
    int base  = batch * NCHUNK_PB + a * (a + 1) + (jt - 2 * a) * (a + 1);
    int nch   = a + 1;

    int tid  = threadIdx.x;
    int row  = rq * 64 + (tid >> 2);     // 0..255
    int c0   = (tid & 3) * 32;

    float Lsum = 0.f;
    f32x4 acc[8];
#pragma unroll
    for (int i = 0; i < 8; i++) acc[i] = (f32x4){0.f, 0.f, 0.f, 0.f};

    for (int c = 0; c < nch; c++) {
        Lsum += ml[(size_t)(base + c) * 256 + row];
        const uint16_t* p = part + (size_t)(base + c) * (256 * 128) + row * 128 + c0;
#pragma unroll
        for (int i = 0; i < 4; i++) {
            us8 v = *(const us8*)(p + i * 8);
#pragma unroll
            for (int j = 0; j < 8; j++)
                acc[i * 2 + (j >> 2)][j & 3] += bf2f(v[j]);
        }
    }
    float inv = 1.f / Lsum;
    size_t orow = (size_t)(batch * T_ + jt * 256 + row);
#pragma unroll
    for (int i = 0; i < 8; i++)
        *(f32x4*)(out + orow * 128 + c0 + i * 4) = acc[i] * inv;
}

// ---------------------------------------------------------------------------
extern "C" void kernel_launch(void* const* d_in, const int* in_sizes, int n_in,
                              void* d_out, int out_size, void* d_ws, size_t ws_size,
                              hipStream_t stream) {
    const float* x  = (const float*)d_in[0];
    const float* Wq = (const float*)d_in[1];
    const float* Wk = (const float*)d_in[2];
    const float* Wv = (const float*)d_in[3];
    float* out = (float*)d_out;

    uint16_t* ws = (uint16_t*)d_ws;
    uint16_t* qb = ws;                                   // 16384*128 bf16
    uint16_t* kb = qb + (size_t)16384 * 128;
    uint16_t* vT = kb + (size_t)16384 * 128;
    uint16_t* WT = vT + (size_t)16384 * 128;             // 3*128*1024
    uint16_t* part = WT + (size_t)3 * D_ * C_;           // 288*256*128 bf16 (x4 batch)
    float* ml = (float*)(part + (size_t)4 * NCHUNK_PB * 256 * 128);  // 288*256 fp32

    prep_w<<<dim3((3 * D_ * C_ + 255) / 256), dim3(256), 0, stream>>>(Wq, Wk, Wv, WT);
    qkv_split<<<dim3(3 * 256), dim3(256), 0, stream>>>(x, WT, qb, kb, vT);
    attn<<<dim3(B_ * NCHUNK_PB), dim3(512), 0, stream>>>(qb, kb, vT, part, ml);
    combine<<<dim3(B_ * 16 * 4), dim3(256), 0, stream>>>(part, ml, out);
}

// Round 9
// 180.125 us; speedup vs baseline: 1.0340x; 1.0340x over previous
//
#include <hip/hip_runtime.h>
#include <stdint.h>

typedef __bf16 bf16_t;
typedef bf16_t bf16x8 __attribute__((ext_vector_type(8)));
typedef float f32x4 __attribute__((ext_vector_type(4)));
typedef float f32x16 __attribute__((ext_vector_type(16)));
typedef unsigned short us8 __attribute__((ext_vector_type(8)));
typedef unsigned short us4 __attribute__((ext_vector_type(4)));
typedef unsigned int u32x4 __attribute__((ext_vector_type(4)));

#define B_ 4
#define T_ 4096
#define C_ 1024
#define D_ 128

#define NCHUNK_PB 144   // per batch: sum over 32 q-tiles(128) of ceil((2jt+2)/8)
#define QSCALE 0.12751744f  // (1/sqrt(128)) * log2(e), folded into Q
#define M0 14.0f            // fixed softmax base (log2 domain); cancels in combine

__device__ __forceinline__ uint16_t f2bf(float f) {
    union { float f; uint32_t u; } v; v.f = f;
    uint32_t u = v.u;
    uint32_t r = (u + 0x7fffu + ((u >> 16) & 1u)) >> 16;
    return (uint16_t)r;
}

// round-half-up bf16 (2 VALU)
__device__ __forceinline__ uint16_t bfru(float f) {
    return (uint16_t)((__float_as_uint(f) + 0x8000u) >> 16);
}

__device__ __forceinline__ float bf2f(uint16_t u) {
    return __uint_as_float((uint32_t)u << 16);
}

// pack 2 f32 -> u32 of 2 bf16 (lo=a, hi=b); no builtin on gfx950 (T12 recipe)
__device__ __forceinline__ uint32_t cvtpk(float a, float b) {
    uint32_t r;
    asm("v_cvt_pk_bf16_f32 %0, %1, %2" : "=v"(r) : "v"(a), "v"(b));
    return r;
}

// v_permlane32_swap_b32: exchanges a.lanes[32:63] <-> b.lanes[0:31].
__device__ __forceinline__ void pl32swap(uint32_t& a, uint32_t& b) {
    asm("v_permlane32_swap_b32 %0, %1" : "+v"(a), "+v"(b));
}

// async global->LDS DMA, 16 B per lane. LDS dest = wave-uniform base + lane*16.
__device__ __forceinline__ void gload_lds16(const void* g, void* l) {
    __builtin_amdgcn_global_load_lds(
        (const __attribute__((address_space(1))) void*)g,
        (__attribute__((address_space(3))) void*)l, 16, 0, 0);
}

// ---------------------------------------------------------------------------
// Kernel 1 (R13): W[C,D] fp32 -> WT[w][n][k] bf16 via LDS tile transpose.
// Old version read W at 512B stride (64 lines/instr, 4B used per 64B line).
// New: 96 blocks, one 64k x 64n tile each: coalesced float4 row reads ->
// bf16 LDS tile (pitch 72 elems = 144B, 16B-aligned) -> 32B row writes.
// ---------------------------------------------------------------------------
__global__ __launch_bounds__(256) void prep_w(const float* __restrict__ Wq,
                                              const float* __restrict__ Wk,
                                              const float* __restrict__ Wv,
                                              uint16_t* __restrict__ WT) {
    __shared__ __align__(16) uint16_t tile[64][72];

    int tid  = threadIdx.x;
    int b    = blockIdx.x;          // 0..95
    int wsel = b >> 5;              // 32 tiles per wsel
    int t    = b & 31;
    int k0   = (t >> 1) << 6;       // 16 k-tiles of 64
    int n0   = (t & 1) << 6;        // 2 n-tiles of 64
    const float* W = (wsel == 0) ? Wq : (wsel == 1) ? Wk : Wv;

    // read: thread covers row r = tid>>2, 16 consecutive n starting at (tid&3)*16
    int r  = tid >> 2;
    int c0 = (tid & 3) << 4;
#pragma unroll
    for (int j = 0; j < 4; j++) {
        float4 f = *(const float4*)&W[(size_t)(k0 + r) * D_ + n0 + c0 + j * 4];
        tile[c0 + j * 4 + 0][r] = f2bf(f.x);
        tile[c0 + j * 4 + 1][r] = f2bf(f.y);
        tile[c0 + j * 4 + 2][r] = f2bf(f.z);
        tile[c0 + j * 4 + 3][r] = f2bf(f.w);
    }
    __syncthreads();

    // write: thread covers n-row n = tid>>2, 16 consecutive k at (tid&3)*16
    int n  = tid >> 2;
    int kc = (tid & 3) << 4;
    uint16_t* dst = WT + (size_t)wsel * D_ * C_ + (size_t)(n0 + n) * C_ + k0 + kc;
    *(us8*)dst       = *(const us8*)&tile[n][kc];
    *(us8*)(dst + 8) = *(const us8*)&tile[n][kc + 8];
}

// ---------------------------------------------------------------------------
// Kernel 2 (R11): wsel-SPLIT QKV projection — unchanged (verified, <47us).
// ---------------------------------------------------------------------------
__global__ __launch_bounds__(256, 3) void qkv_split(const float* __restrict__ x,
                                                    const uint16_t* __restrict__ WT,
                                                    uint16_t* __restrict__ qb,
                                                    uint16_t* __restrict__ kb,
                                                    uint16_t* __restrict__ vT) {
    __shared__ __align__(16) float    A_lds[2][64 * 32];    // 2 x 8 KB (fp32)
    __shared__ __align__(16) uint16_t W_lds[2][128 * 32];   // 2 x 8 KB (bf16)

    int tid  = threadIdx.x;
    int lane = tid & 63;
    int wave = tid >> 6;          // 0..3
    int quad = lane >> 4;
    int lx   = lane & 15;
    int wm   = wave >> 1;         // 0..1 : 32-row half
    int wn   = wave & 1;          // 0..1 : 64-col half

    int bx   = blockIdx.x;
    int wsel = bx >> 8;           // 0..2 (Q/K/V)
    int m0   = (bx & 255) * 64;
    const uint16_t* Wp = WT + (size_t)wsel * (D_ * C_);

    auto issue_ab = [&](int bi, int k0) {
#pragma unroll
        for (int j = 0; j < 2; j++) {
            int rbase = wave * 16 + j * 8;
            int row   = rbase + (lane >> 3);
            int gch   = (lane & 7) ^ (row & 7);
            gload_lds16(x + (size_t)(m0 + row) * C_ + k0 + gch * 4,
                        &A_lds[bi][rbase * 32]);
        }
#pragma unroll
        for (int j = 0; j < 2; j++) {
            int rbase = wave * 32 + j * 16;
            int row   = rbase + (lane >> 2);
            int gch   = (lane & 3) ^ ((row >> 1) & 3);
            gload_lds16(Wp + (size_t)row * C_ + k0 + gch * 8,
                        &W_lds[bi][rbase * 32]);
        }
    };

    f32x4 acc[2][4];
#pragma unroll
    for (int mf = 0; mf < 2; mf++)
#pragma unroll
        for (int nf = 0; nf < 4; nf++)
            acc[mf][nf] = (f32x4){0.f, 0.f, 0.f, 0.f};

    issue_ab(0, 0);   // prologue prefetch
    int cur = 0;

    for (int k0 = 0; k0 < C_; k0 += 32) {
        __syncthreads();
        if (k0 + 32 < C_) issue_ab(cur ^ 1, k0 + 32);

        bf16x8 af[2];
#pragma unroll
        for (int mf = 0; mf < 2; mf++) {
            int arow = wm * 32 + mf * 16 + lx;
            const float* ar = &A_lds[cur][arow * 32];
            f32x4 a0 = *(const f32x4*)&ar[((2 * quad) ^ (arow & 7)) * 4];
            f32x4 a1 = *(const f32x4*)&ar[((2 * quad + 1) ^ (arow & 7)) * 4];
            u32x4 w = (u32x4){cvtpk(a0[0], a0[1]), cvtpk(a0[2], a0[3]),
                              cvtpk(a1[0], a1[1]), cvtpk(a1[2], a1[3])};
            af[mf] = *(bf16x8*)&w;
        }

#pragma unroll
        for (int nf = 0; nf < 4; nf++) {
            int n = wn * 64 + nf * 16 + lx;
            bf16x8 wf = *(const bf16x8*)&W_lds[cur][n * 32 + ((quad ^ ((n >> 1) & 3)) * 8)];
            acc[0][nf] = __builtin_amdgcn_mfma_f32_16x16x32_bf16(af[0], wf, acc[0][nf], 0, 0, 0);
            acc[1][nf] = __builtin_amdgcn_mfma_f32_16x16x32_bf16(af[1], wf, acc[1][nf], 0, 0, 0);
        }
        cur ^= 1;
    }

#pragma unroll
    for (int mf = 0; mf < 2; mf++) {
        int mrow0 = m0 + wm * 32 + mf * 16 + quad * 4;
        int batch = mrow0 >> 12;
        int t     = mrow0 & 4095;
#pragma unroll
        for (int nf = 0; nf < 4; nf++) {
            int n = wn * 64 + nf * 16 + lx;
            if (wsel == 0) {
#pragma unroll
                for (int r = 0; r < 4; r++)
                    qb[(size_t)(mrow0 + r) * D_ + n] = bfru(acc[mf][nf][r] * QSCALE);
            } else if (wsel == 1) {
#pragma unroll
                for (int r = 0; r < 4; r++)
                    kb[(size_t)(mrow0 + r) * D_ + n] = bfru(acc[mf][nf][r]);
            } else {
                us4 pv;
#pragma unroll
                for (int r = 0; r < 4; r++) pv[r] = bfru(acc[mf][nf][r]);
                *(us4*)&vT[(size_t)batch * D_ * T_ + (size_t)n * T_ + t] = pv;
            }
        }
    }
}

// ---------------------------------------------------------------------------
// Kernel 3: split-K flash attention — R11 version verbatim (verified 47.2us:
// 4-wave blocks, 576 grid = 2+ independent barrier domains/CU; R12's 8-wave
// 288-grid variant had the same waves/CU in ONE lockstep domain -> slower).
// ---------------------------------------------------------------------------
__global__ __launch_bounds__(512, 2) void attn_dummy_decl(); // (placeholder removed)

__global__ __launch_bounds__(256, 2) void attn(const uint16_t* __restrict__ qb,
                                               const uint16_t* __restrict__ kb,
                                               const uint16_t* __restrict__ vT,
                                               uint16_t* __restrict__ part,
                                               float* __restrict__ ml) {
    __shared__ __align__(16) uint16_t K_lds[2][64 * 128];    // 2 x 16384 B
    __shared__ __align__(16) uint16_t V_lds[2][128 * 64];    // 2 x 16384 B

    int tid  = threadIdx.x;
    int lane = tid & 63;
    int wave = tid >> 6;
    int q31  = lane & 31;   // q column (and key-row / d-row index in frags)
    int hi   = lane >> 5;   // kb group

    // decode blockIdx -> (batch, logical chunk L), longest chunks first.
    int batch = blockIdx.x & 3;
    int L     = NCHUNK_PB - 1 - (blockIdx.x >> 2);
    int a = 0;
    while (a < 7 && 2 * (a + 1) * (a + 2) <= L) a++;
    int rem   = L - 2 * a * (a + 1);
    int jt    = 4 * a + rem / (a + 1);
    int chunk = rem - (rem / (a + 1)) * (a + 1);
    int lidx  = batch * NCHUNK_PB + L;

    int q0     = jt * 128;
    int st0    = chunk * 8;
    int ntiles = min(8, 2 * jt + 2 - st0);

    // issue one K+V 64-key tile into buffer bi via DMA.
    auto issue_kv = [&](int bi, int tile) {
        int s0i = tile * 64;
        const uint16_t* kB = kb + (size_t)(batch * T_ + s0i) * D_;
#pragma unroll
        for (int j = 0; j < 4; j++) {
            int row = wave * 16 + j * 4 + (lane >> 4);
            int gch = (lane & 15) ^ (row & 7);
            gload_lds16(kB + (size_t)row * D_ + gch * 8,
                        &K_lds[bi][(wave * 16 + j * 4) * 128]);
        }
        const uint16_t* vB = vT + (size_t)batch * D_ * T_ + s0i;
#pragma unroll
        for (int j = 0; j < 4; j++) {
            int row = wave * 32 + j * 8 + (lane >> 3);
            int gch = (lane & 7) ^ (row & 7);
            gload_lds16(vB + (size_t)row * T_ + gch * 8,
                        &V_lds[bi][(wave * 32 + j * 8) * 64]);
        }
    };

    // Q fragments (B operand): lane = q + 32*kb holds d = kc*16 + kb*8 + j
    bf16x8 qf[8];
    {
        const uint16_t* qp = qb + (size_t)(batch * T_ + q0 + wave * 32 + q31) * D_ + hi * 8;
#pragma unroll
        for (int kc = 0; kc < 8; kc++) qf[kc] = *(const bf16x8*)(qp + kc * 16);
    }

    f32x16 o[4];
#pragma unroll
    for (int i = 0; i < 4; i++)
#pragma unroll
        for (int r = 0; r < 16; r++) o[i][r] = 0.f;
    float lsum = 0.f;

    issue_kv(0, st0);   // prologue prefetch
    int cur = 0;

    for (int it = 0; it < ntiles; it++) {
        int s0 = (st0 + it) * 64;
        // drains this wave's DMA (vmcnt(0) implicit) -> buf[cur] ready;
        // also guarantees all waves finished reading buf[cur^1] last iter.
        __syncthreads();
        if (it + 1 < ntiles) issue_kv(cur ^ 1, st0 + it + 1);

        // S^T = K Q^T (A = K-frag, B = Q-frag), 2 s-tiles of 32
        f32x16 st[2];
#pragma unroll
        for (int nt = 0; nt < 2; nt++)
#pragma unroll
            for (int r = 0; r < 16; r++) st[nt][r] = 0.f;
        __builtin_amdgcn_s_setprio(1);
#pragma unroll
        for (int kc = 0; kc < 8; kc++)
#pragma unroll
            for (int nt = 0; nt < 2; nt++) {
                int row = nt * 32 + q31;
                bf16x8 kf = *(const bf16x8*)&K_lds[cur][row * 128 + (((kc * 2 + hi) ^ (row & 7)) * 8)];
                st[nt] = __builtin_amdgcn_mfma_f32_32x32x16_bf16(kf, qf[kc], st[nt], 0, 0, 0);
            }
        __builtin_amdgcn_s_setprio(0);

        // causal mask on diagonal-region tiles (wave-uniform branch)
        if (st0 + it >= 2 * jt) {
            int qg = q0 + wave * 32 + q31;
#pragma unroll
            for (int nt = 0; nt < 2; nt++)
#pragma unroll
                for (int r = 0; r < 16; r++) {
                    int sg = s0 + nt * 32 + (r & 3) + 8 * (r >> 2) + 4 * hi;
                    if (sg > qg) st[nt][r] = -INFINITY;
                }
        }

        // p = exp2(s - M0); accumulate denominator per-lane (one q per lane)
#pragma unroll
        for (int nt = 0; nt < 2; nt++)
#pragma unroll
            for (int r = 0; r < 16; r++) {
                st[nt][r] = exp2f(st[nt][r] - M0);
                lsum += st[nt][r];
            }

        // build PV A-frags in-register: 16 cvt_pk + 8 permlane32_swap.
        // pa[sb] reg j at lane(q,hi) = P[q][sb*16 + hi*8 + 2j, +2j+1]
        bf16x8 pa[4];
#pragma unroll
        for (int nt = 0; nt < 2; nt++) {
            uint32_t x0 = cvtpk(st[nt][0],  st[nt][1]);
            uint32_t x1 = cvtpk(st[nt][2],  st[nt][3]);
            uint32_t y0 = cvtpk(st[nt][4],  st[nt][5]);
            uint32_t y1 = cvtpk(st[nt][6],  st[nt][7]);
            pl32swap(x0, y0);
            pl32swap(x1, y1);
            u32x4 w0 = (u32x4){x0, x1, y0, y1};
            pa[2 * nt] = *(bf16x8*)&w0;
            uint32_t z0 = cvtpk(st[nt][8],  st[nt][9]);
            uint32_t z1 = cvtpk(st[nt][10], st[nt][11]);
            uint32_t t0 = cvtpk(st[nt][12], st[nt][13]);
            uint32_t t1 = cvtpk(st[nt][14], st[nt][15]);
            pl32swap(z0, t0);
            pl32swap(z1, t1);
            u32x4 w1 = (u32x4){z0, z1, t0, t1};
            pa[2 * nt + 1] = *(bf16x8*)&w1;
        }

        // O += P V : A = pa[sb] (q x 16s), B = V-frag from vT layout [d][s]
        __builtin_amdgcn_s_setprio(1);
#pragma unroll
        for (int sb = 0; sb < 4; sb++)
#pragma unroll
            for (int ntd = 0; ntd < 4; ntd++) {
                int row = ntd * 32 + q31;
                bf16x8 vf = *(const bf16x8*)&V_lds[cur][row * 64 + (((sb * 2 + hi) ^ (row & 7)) * 8)];
                o[ntd] = __builtin_amdgcn_mfma_f32_32x32x16_bf16(pa[sb], vf, o[ntd], 0, 0, 0);
            }
        __builtin_amdgcn_s_setprio(0);
        cur ^= 1;
    }

    // each q's denominator is split across lane and lane^32
    lsum += __shfl_xor(lsum, 32, 64);

    // write unnormalized partial (bf16) + l at the LOGICAL index.
    // O tile: col=lane&31 = d (within ntd*32), row = (r&3)+8*(r>>2)+4*hi = q
    uint16_t* pp = part + (size_t)lidx * (128 * 128);
#pragma unroll
    for (int ntd = 0; ntd < 4; ntd++)
#pragma unroll
        for (int r = 0; r < 16; r++) {
            int lrow = wave * 32 + (r & 3) + 8 * (r >> 2) + 4 * hi;
            pp[lrow * 128 + ntd * 32 + q31] = bfru(o[ntd][r]);
        }
    if (lane < 32)
        ml[(size_t)lidx * 128 + wave * 32 + q31] = lsum;
}

// ---------------------------------------------------------------------------
// Kernel 4: combine split-K partials — R11 version verbatim.
// ---------------------------------------------------------------------------
__global__ __launch_bounds__(256) void combine(const uint16_t* __restrict__ part,
                                               const float* __restrict__ ml,
                                               float* __restrict__ out) {
    int bidx  = blockIdx.x;
    int half  = bidx & 1;
    int jt    = (bidx >> 1) & 31;
    int batch = bidx >> 6;
    int a     = jt >> 2;
    int base  = batch * NCHUNK_PB + 2 * a * (a + 1) + (jt - 4 * a) * (a + 1);
    int nch   = a + 1;

    int tid  = threadIdx.x;
    int lrow = tid >> 1;                 // 0..127
    int c0   = half * 64 + (tid & 1) * 32;

    float Lsum = 0.f;
    f32x4 acc[8];
#pragma unroll
    for (int i = 0; i < 8; i++) acc[i] = (f32x4){0.f, 0.f, 0.f, 0.f};

    for (int c = 0; c < nch; c++) {
        Lsum += ml[(size_t)(base + c) * 128 + lrow];
        const uint16_t* p = part + (size_t)(base + c) * (128 * 128) + lrow * 128 + c0;
#pragma unroll
        for (int i = 0; i < 4; i++) {
            us8 v = *(const us8*)(p + i * 8);
#pragma unroll
            for (int j = 0; j < 8; j++)
                acc[i * 2 + (j >> 2)][j & 3] += bf2f(v[j]);
        }
    }
    float inv = 1.f / Lsum;
    size_t row = (size_t)(batch * T_ + jt * 128 + lrow);
#pragma unroll
    for (int i = 0; i < 8; i++)
        *(f32x4*)(out + row * 128 + c0 + i * 4) = acc[i] * inv;
}

// ---------------------------------------------------------------------------
extern "C" void kernel_launch(void* const* d_in, const int* in_sizes, int n_in,
                              void* d_out, int out_size, void* d_ws, size_t ws_size,
                              hipStream_t stream) {
    const float* x  = (const float*)d_in[0];
    const float* Wq = (const float*)d_in[1];
    const float* Wk = (const float*)d_in[2];
    const float* Wv = (const float*)d_in[3];
    float* out = (float*)d_out;

    uint16_t* ws = (uint16_t*)d_ws;
    uint16_t* qb = ws;                                   // 16384*128 bf16
    uint16_t* kb = qb + (size_t)16384 * 128;
    uint16_t* vT = kb + (size_t)16384 * 128;
    uint16_t* WT = vT + (size_t)16384 * 128;             // 3*128*1024
    uint16_t* part = WT + (size_t)3 * D_ * C_;           // 576*128*128 bf16
    float* ml = (float*)(part + (size_t)4 * NCHUNK_PB * 128 * 128);  // 576*128 fp32

    prep_w<<<dim3(96), dim3(256), 0, stream>>>(Wq, Wk, Wv, WT);
    qkv_split<<<dim3(3 * 256), dim3(256), 0, stream>>>(x, WT, qb, kb, vT);
    attn<<<dim3(B_ * NCHUNK_PB), dim3(256), 0, stream>>>(qb, kb, vT, part, ml);
    combine<<<dim3(B_ * 32 * 2), dim3(256), 0, stream>>>(part, ml, out);
}